// Round 1
// baseline (368.838 us; speedup 1.0000x reference)
//
#include <hip/hip_runtime.h>
#include <hip/hip_bf16.h>
#include <math.h>

typedef __bf16 bf16;
typedef bf16 bf16x8 __attribute__((ext_vector_type(8)));
typedef bf16 bf16x4v __attribute__((ext_vector_type(4)));
typedef float f32x4 __attribute__((ext_vector_type(4)));

#define GLD16(g, l) __builtin_amdgcn_global_load_lds(                          \
    (__attribute__((address_space(1))) void*)(g),                              \
    (__attribute__((address_space(3))) void*)(l), 16, 0, 0)

#define MFMA16(a, b, c) __builtin_amdgcn_mfma_f32_16x16x32_bf16((a), (b), (c), 0, 0, 0)

__device__ __forceinline__ f32x4 shfl_xor4(f32x4 a, int m) {
  f32x4 r;
  #pragma unroll
  for (int i = 0; i < 4; i++) r[i] = __shfl_xor(a[i], m);
  return r;
}

// ---------------- cast f32 -> bf16 (vectorized) ----------------
__global__ void cast_f32_bf16(const float* __restrict__ in, bf16* __restrict__ out, int n4) {
  int i = blockIdx.x * blockDim.x + threadIdx.x;
  if (i < n4) {
    float4 v = ((const float4*)in)[i];
    bf16x4v o;
    o.x = (bf16)v.x; o.y = (bf16)v.y; o.z = (bf16)v.z; o.w = (bf16)v.w;
    ((bf16x4v*)out)[i] = o;
  }
}

// ---------------- transpose + cast: out[off + c][r] = in[r][c] ----------------
__global__ void transpose_cast(const float* __restrict__ in, bf16* __restrict__ out,
                               int colsIn, int outStride, int outRowOff) {
  __shared__ float t[32][33];
  int c0 = blockIdx.x * 32, r0 = blockIdx.y * 32;
  int tx = threadIdx.x, ty = threadIdx.y;  // block (32,8)
  #pragma unroll
  for (int i = 0; i < 32; i += 8)
    t[ty + i][tx] = in[(size_t)(r0 + ty + i) * colsIn + (c0 + tx)];
  __syncthreads();
  #pragma unroll
  for (int i = 0; i < 32; i += 8)
    out[(size_t)(outRowOff + c0 + ty + i) * outStride + (r0 + tx)] = (bf16)t[tx][ty + i];
}

// ---------------- m97-style GEMM: A[M][K] bf16, Bt[N][K] bf16 -> C[M][N] ----------------
// 128x128 tile, BK=32, 4 waves (2x2), 4x4 16x16x32 MFMA per wave.
template <typename OutT>
__global__ __launch_bounds__(256, 2) void gemm_bt(const bf16* __restrict__ A,
                                                  const bf16* __restrict__ Bt,
                                                  OutT* __restrict__ C,
                                                  int M, int N, int K) {
  __shared__ __attribute__((aligned(16))) bf16 As[128 * 32];
  __shared__ __attribute__((aligned(16))) bf16 Bs[128 * 32];
  const int tid = threadIdx.x;
  const int lane = tid & 63;
  const int wave = tid >> 6;
  const int wm = wave >> 1, wn = wave & 1;
  const int l15 = lane & 15, quad = lane >> 4;
  const int rowBase = blockIdx.y * 128;
  const int colBase = blockIdx.x * 128;

  f32x4 acc[4][4] = {};

  // staging: 512 16B-chunks per tile; chunk c -> row c>>2, k-chunk c&3
  const int cb0 = wave * 64;
  const int c0 = cb0 + lane;
  const int c1 = c0 + 256;
  const bf16* a0 = A + (size_t)(rowBase + (c0 >> 2)) * K + (c0 & 3) * 8;
  const bf16* a1 = A + (size_t)(rowBase + (c1 >> 2)) * K + (c1 & 3) * 8;
  const bf16* b0 = Bt + (size_t)(colBase + (c0 >> 2)) * K + (c0 & 3) * 8;
  const bf16* b1 = Bt + (size_t)(colBase + (c1 >> 2)) * K + (c1 & 3) * 8;
  bf16* lA0 = &As[cb0 * 8];
  bf16* lA1 = &As[(cb0 + 256) * 8];
  bf16* lB0 = &Bs[cb0 * 8];
  bf16* lB1 = &Bs[(cb0 + 256) * 8];

  for (int k0 = 0; k0 < K; k0 += 32) {
    GLD16(a0 + k0, lA0);
    GLD16(a1 + k0, lA1);
    GLD16(b0 + k0, lB0);
    GLD16(b1 + k0, lB1);
    __syncthreads();
    bf16x8 af[4], bfr[4];
    #pragma unroll
    for (int i = 0; i < 4; i++)
      af[i] = *(const bf16x8*)&As[(wm * 64 + i * 16 + l15) * 32 + quad * 8];
    #pragma unroll
    for (int i = 0; i < 4; i++)
      bfr[i] = *(const bf16x8*)&Bs[(wn * 64 + i * 16 + l15) * 32 + quad * 8];
    #pragma unroll
    for (int i = 0; i < 4; i++)
      #pragma unroll
      for (int j = 0; j < 4; j++)
        acc[i][j] = MFMA16(af[i], bfr[j], acc[i][j]);
    __syncthreads();
  }

  #pragma unroll
  for (int i = 0; i < 4; i++) {
    int row = rowBase + wm * 64 + i * 16 + quad * 4;
    #pragma unroll
    for (int j = 0; j < 4; j++) {
      int col = colBase + wn * 64 + j * 16 + l15;
      #pragma unroll
      for (int r = 0; r < 4; r++)
        C[(size_t)(row + r) * N + col] = (OutT)acc[i][j][r];
    }
  }
}

// ---------------- flash-style GQA attention ----------------
// QKV layout: [B*N][3072] bf16 : cols 0..2047 Q(h*128+d), 2048..2559 K(kvh*128+d),
// 2560..3071 V(kvh*128+d). Output Obf: [B*N][2048] bf16 (h*128+d).
#define SCALE_F 0.08838834764831845f
#define L2E 1.4426950408889634f
#define MASKV (-1e30f)

__global__ __launch_bounds__(256, 2) void gqa_attn(const bf16* __restrict__ QKV,
                                                   bf16* __restrict__ Obf) {
  __shared__ __attribute__((aligned(16))) bf16 Kl[64 * 152];      // [key][hd], pad->152
  __shared__ __attribute__((aligned(16))) bf16 Vt[128 * 72];      // [hd][key], pad->72
  __shared__ __attribute__((aligned(16))) bf16 Pl[4][32 * 72];    // per-wave P, pad->72

  const int tid = threadIdx.x;
  const int lane = tid & 63;
  const int wave = tid >> 6;
  const int l15 = lane & 15, quad = lane >> 4;

  // balanced mapping: block i<256 -> heavy q-tiles (8..15), i>=256 -> light (7..0);
  // CU c typically hosts blocks c and c+256 -> ~constant work per CU.
  int bi = blockIdx.x;
  int bh = bi & 31;
  int jj = (bi & 255) >> 5;
  int qt = (bi < 256) ? (8 + jj) : (7 - jj);
  int b = bh >> 4, h = bh & 15, kvh = h >> 2;
  int q0 = qt * 128;

  const size_t rs = 3072;
  const bf16* Qb = QKV + (size_t)b * 2048 * rs + h * 128;
  const bf16* Kb = QKV + (size_t)b * 2048 * rs + 2048 + kvh * 128;
  const bf16* Vb = QKV + (size_t)b * 2048 * rs + 2560 + kvh * 128;

  // Q fragments: wave owns rows [q0+wave*32, +32) -> 2 m-tiles x 4 k-steps
  bf16x8 qf[2][4];
  #pragma unroll
  for (int mt = 0; mt < 2; mt++) {
    int row = q0 + wave * 32 + mt * 16 + l15;
    #pragma unroll
    for (int ks = 0; ks < 4; ks++)
      qf[mt][ks] = *(const bf16x8*)&Qb[(size_t)row * rs + ks * 32 + quad * 8];
  }

  f32x4 oacc[2][8] = {};
  f32x4 mrow[2], lrow[2];
  #pragma unroll
  for (int mt = 0; mt < 2; mt++)
    #pragma unroll
    for (int r = 0; r < 4; r++) { mrow[mt][r] = MASKV; lrow[mt][r] = 0.f; }

  const int nkt = 2 * qt + 2;  // key tiles of 64 covering [0, q0+128)
  for (int kt = 0; kt < nkt; kt++) {
    const int k0 = kt * 64;
    __syncthreads();  // previous tile fully consumed
    // stage K tile [64][128] -> Kl[key*152 + hd] (coalesced read, seq LDS write)
    #pragma unroll
    for (int it = 0; it < 4; it++) {
      int c = it * 256 + tid;
      int key = c >> 4, hc = c & 15;
      bf16x8 v = *(const bf16x8*)&Kb[(size_t)(k0 + key) * rs + hc * 8];
      *(bf16x8*)&Kl[key * 152 + hc * 8] = v;
    }
    // stage V transposed: Vt[hd*72 + key] (lane-per-key -> conflict-free LDS writes)
    #pragma unroll
    for (int it = 0; it < 4; it++) {
      int c = it * 256 + tid;
      int key = c & 63, hc = c >> 6;
      bf16x8 v = *(const bf16x8*)&Vb[(size_t)(k0 + key) * rs + hc * 8];
      #pragma unroll
      for (int j2 = 0; j2 < 8; j2++) Vt[(hc * 8 + j2) * 72 + key] = v[j2];
    }
    __syncthreads();

    // wave with all rows < k0 contributes nothing for this tile (fully masked)
    if (k0 > q0 + wave * 32 + 31) continue;

    // S = Q K^T  (2 m-tiles x 4 n-tiles)
    f32x4 s[2][4] = {};
    #pragma unroll
    for (int nt = 0; nt < 4; nt++) {
      #pragma unroll
      for (int ks = 0; ks < 4; ks++) {
        bf16x8 kf = *(const bf16x8*)&Kl[(nt * 16 + l15) * 152 + ks * 32 + quad * 8];
        s[0][nt] = MFMA16(qf[0][ks], kf, s[0][nt]);
        s[1][nt] = MFMA16(qf[1][ks], kf, s[1][nt]);
      }
    }
    // scale + causal mask (only last two tiles intersect the diagonal)
    bool diag = (kt >= nkt - 2);
    #pragma unroll
    for (int mt = 0; mt < 2; mt++)
      #pragma unroll
      for (int nt = 0; nt < 4; nt++)
        #pragma unroll
        for (int r = 0; r < 4; r++) {
          float v = s[mt][nt][r] * SCALE_F;
          if (diag) {
            int col = k0 + nt * 16 + l15;
            int row = q0 + wave * 32 + mt * 16 + quad * 4 + r;
            if (col > row) v = MASKV;
          }
          s[mt][nt][r] = v;
        }
    // online softmax (row stats live in C-layout: row = quad*4+r, cols across 16 lanes)
    #pragma unroll
    for (int mt = 0; mt < 2; mt++) {
      f32x4 mx = s[mt][0];
      #pragma unroll
      for (int nt = 1; nt < 4; nt++)
        #pragma unroll
        for (int r = 0; r < 4; r++) mx[r] = fmaxf(mx[r], s[mt][nt][r]);
      #pragma unroll
      for (int d = 1; d < 16; d <<= 1) {
        f32x4 o = shfl_xor4(mx, d);
        #pragma unroll
        for (int r = 0; r < 4; r++) mx[r] = fmaxf(mx[r], o[r]);
      }
      f32x4 mnew, alpha;
      #pragma unroll
      for (int r = 0; r < 4; r++) {
        mnew[r] = fmaxf(mrow[mt][r], mx[r]);
        alpha[r] = exp2f((mrow[mt][r] - mnew[r]) * L2E);
      }
      f32x4 rsum = {0.f, 0.f, 0.f, 0.f};
      #pragma unroll
      for (int nt = 0; nt < 4; nt++)
        #pragma unroll
        for (int r = 0; r < 4; r++) {
          float p = exp2f((s[mt][nt][r] - mnew[r]) * L2E);
          s[mt][nt][r] = p;
          rsum[r] += p;
        }
      #pragma unroll
      for (int d = 1; d < 16; d <<= 1) rsum += shfl_xor4(rsum, d);
      #pragma unroll
      for (int r = 0; r < 4; r++) {
        lrow[mt][r] = lrow[mt][r] * alpha[r] + rsum[r];
        mrow[mt][r] = mnew[r];
      }
      #pragma unroll
      for (int no = 0; no < 8; no++)
        #pragma unroll
        for (int r = 0; r < 4; r++) oacc[mt][no][r] *= alpha[r];
      // P: C-layout -> LDS (A-layout consumable)
      #pragma unroll
      for (int nt = 0; nt < 4; nt++)
        #pragma unroll
        for (int r = 0; r < 4; r++)
          Pl[wave][(mt * 16 + quad * 4 + r) * 72 + nt * 16 + l15] = (bf16)s[mt][nt][r];
    }
    // O += P V   (2 k-steps of 32 keys, 8 hd-tiles)
    #pragma unroll
    for (int ks2 = 0; ks2 < 2; ks2++) {
      bf16x8 pf0 = *(const bf16x8*)&Pl[wave][(l15) * 72 + ks2 * 32 + quad * 8];
      bf16x8 pf1 = *(const bf16x8*)&Pl[wave][(16 + l15) * 72 + ks2 * 32 + quad * 8];
      #pragma unroll
      for (int no = 0; no < 8; no++) {
        bf16x8 vf = *(const bf16x8*)&Vt[(no * 16 + l15) * 72 + ks2 * 32 + quad * 8];
        oacc[0][no] = MFMA16(pf0, vf, oacc[0][no]);
        oacc[1][no] = MFMA16(pf1, vf, oacc[1][no]);
      }
    }
  }

  // epilogue: normalize and write bf16
  #pragma unroll
  for (int mt = 0; mt < 2; mt++) {
    f32x4 linv;
    #pragma unroll
    for (int r = 0; r < 4; r++) linv[r] = 1.0f / lrow[mt][r];
    int row = q0 + wave * 32 + mt * 16 + quad * 4;
    #pragma unroll
    for (int no = 0; no < 8; no++) {
      int col = h * 128 + no * 16 + l15;
      #pragma unroll
      for (int r = 0; r < 4; r++)
        Obf[(size_t)(b * 2048 + row + r) * 2048 + col] = (bf16)(oacc[mt][no][r] * linv[r]);
    }
  }
}

extern "C" void kernel_launch(void* const* d_in, const int* in_sizes, int n_in,
                              void* d_out, int out_size, void* d_ws, size_t ws_size,
                              hipStream_t stream) {
  const float* x  = (const float*)d_in[0];
  // d_in[1] = mask: always causal tril; handled analytically.
  const float* Wq = (const float*)d_in[2];
  const float* Wk = (const float*)d_in[3];
  const float* Wv = (const float*)d_in[4];
  const float* Wo = (const float*)d_in[5];
  float* out = (float*)d_out;

  // workspace layout (bf16 elements)
  bf16* Xb    = (bf16*)d_ws;           // 4096x2048
  bf16* Wqkvt = Xb + 8388608;          // 3072x2048 (transposed, fused Q|K|V)
  bf16* Wot   = Wqkvt + 6291456;       // 2048x2048 (transposed)
  bf16* QKV   = Wot + 4194304;         // 4096x3072
  bf16* Obf   = QKV + 12582912;        // 4096x2048
  // total 79,691,776 bytes

  cast_f32_bf16<<<8192, 256, 0, stream>>>(x, Xb, 2097152);
  dim3 tb(32, 8);
  transpose_cast<<<dim3(64, 64), tb, 0, stream>>>(Wq, Wqkvt, 2048, 2048, 0);
  transpose_cast<<<dim3(16, 64), tb, 0, stream>>>(Wk, Wqkvt, 512, 2048, 2048);
  transpose_cast<<<dim3(16, 64), tb, 0, stream>>>(Wv, Wqkvt, 512, 2048, 2560);
  transpose_cast<<<dim3(64, 64), tb, 0, stream>>>(Wo, Wot, 2048, 2048, 0);

  gemm_bt<bf16><<<dim3(24, 32), 256, 0, stream>>>(Xb, Wqkvt, QKV, 4096, 3072, 2048);
  gqa_attn<<<512, 256, 0, stream>>>(QKV, Obf);
  gemm_bt<float><<<dim3(16, 32), 256, 0, stream>>>(Obf, Wot, out, 4096, 2048, 2048);
}

// Round 2
// 339.039 us; speedup vs baseline: 1.0879x; 1.0879x over previous
//
#include <hip/hip_runtime.h>
#include <hip/hip_bf16.h>
#include <math.h>

typedef __bf16 bf16;
typedef bf16 bf16x8 __attribute__((ext_vector_type(8)));
typedef bf16 bf16x4v __attribute__((ext_vector_type(4)));
typedef float f32x4 __attribute__((ext_vector_type(4)));

#define GLD16(g, l) __builtin_amdgcn_global_load_lds(                          \
    (__attribute__((address_space(1))) void*)(g),                              \
    (__attribute__((address_space(3))) void*)(l), 16, 0, 0)

#define MFMA16(a, b, c) __builtin_amdgcn_mfma_f32_16x16x32_bf16((a), (b), (c), 0, 0, 0)

#if __has_builtin(__builtin_amdgcn_exp2f)
#define EXP2F(x) __builtin_amdgcn_exp2f(x)
#else
#define EXP2F(x) exp2f(x)
#endif

__device__ __forceinline__ f32x4 shfl_xor4(f32x4 a, int m) {
  f32x4 r;
  #pragma unroll
  for (int i = 0; i < 4; i++) r[i] = __shfl_xor(a[i], m);
  return r;
}

// ---------------- cast f32 -> bf16 (vectorized) ----------------
__global__ void cast_f32_bf16(const float* __restrict__ in, bf16* __restrict__ out, int n4) {
  int i = blockIdx.x * blockDim.x + threadIdx.x;
  if (i < n4) {
    float4 v = ((const float4*)in)[i];
    bf16x4v o;
    o.x = (bf16)v.x; o.y = (bf16)v.y; o.z = (bf16)v.z; o.w = (bf16)v.w;
    ((bf16x4v*)out)[i] = o;
  }
}

// ---------------- transpose + cast + scale: out[off + c][r] = in[r][c]*scale ----------------
__global__ void transpose_cast(const float* __restrict__ in, bf16* __restrict__ out,
                               int colsIn, int outStride, int outRowOff, float scale) {
  __shared__ float t[32][33];
  int c0 = blockIdx.x * 32, r0 = blockIdx.y * 32;
  int tx = threadIdx.x, ty = threadIdx.y;  // block (32,8)
  #pragma unroll
  for (int i = 0; i < 32; i += 8)
    t[ty + i][tx] = in[(size_t)(r0 + ty + i) * colsIn + (c0 + tx)];
  __syncthreads();
  #pragma unroll
  for (int i = 0; i < 32; i += 8)
    out[(size_t)(outRowOff + c0 + ty + i) * outStride + (r0 + tx)] = (bf16)(t[tx][ty + i] * scale);
}

// ---------------- V -> V^T global: Vg[(b*4+kvh)][d][n] = QKV[b*2048+n][2560+kvh*128+d] ----------------
__global__ void transpose_v(const bf16* __restrict__ QKV, bf16* __restrict__ Vg) {
  __shared__ bf16 t[32][34];
  int n0 = blockIdx.x * 32, d0 = blockIdx.y * 32;
  int bk = blockIdx.z;
  int b = bk >> 2, kvh = bk & 3;
  const bf16* src = QKV + (size_t)b * 2048 * 3072 + 2560 + kvh * 128;
  bf16* dst = Vg + (size_t)bk * 128 * 2048;
  int tx = threadIdx.x, ty = threadIdx.y;  // block (32,8)
  #pragma unroll
  for (int i = 0; i < 32; i += 8)
    t[ty + i][tx] = src[(size_t)(n0 + ty + i) * 3072 + (d0 + tx)];
  __syncthreads();
  #pragma unroll
  for (int i = 0; i < 32; i += 8)
    dst[(size_t)(d0 + ty + i) * 2048 + (n0 + tx)] = t[tx][ty + i];
}

// ---------------- m97-style GEMM: A[M][K] bf16, Bt[N][K] bf16 -> C[M][N] ----------------
template <typename OutT>
__global__ __launch_bounds__(256, 2) void gemm_bt(const bf16* __restrict__ A,
                                                  const bf16* __restrict__ Bt,
                                                  OutT* __restrict__ C,
                                                  int M, int N, int K) {
  __shared__ __attribute__((aligned(16))) bf16 As[128 * 32];
  __shared__ __attribute__((aligned(16))) bf16 Bs[128 * 32];
  const int tid = threadIdx.x;
  const int lane = tid & 63;
  const int wave = tid >> 6;
  const int wm = wave >> 1, wn = wave & 1;
  const int l15 = lane & 15, quad = lane >> 4;
  const int rowBase = blockIdx.y * 128;
  const int colBase = blockIdx.x * 128;

  f32x4 acc[4][4] = {};

  const int cb0 = wave * 64;
  const int c0 = cb0 + lane;
  const int c1 = c0 + 256;
  const bf16* a0 = A + (size_t)(rowBase + (c0 >> 2)) * K + (c0 & 3) * 8;
  const bf16* a1 = A + (size_t)(rowBase + (c1 >> 2)) * K + (c1 & 3) * 8;
  const bf16* b0 = Bt + (size_t)(colBase + (c0 >> 2)) * K + (c0 & 3) * 8;
  const bf16* b1 = Bt + (size_t)(colBase + (c1 >> 2)) * K + (c1 & 3) * 8;
  bf16* lA0 = &As[cb0 * 8];
  bf16* lA1 = &As[(cb0 + 256) * 8];
  bf16* lB0 = &Bs[cb0 * 8];
  bf16* lB1 = &Bs[(cb0 + 256) * 8];

  for (int k0 = 0; k0 < K; k0 += 32) {
    GLD16(a0 + k0, lA0);
    GLD16(a1 + k0, lA1);
    GLD16(b0 + k0, lB0);
    GLD16(b1 + k0, lB1);
    __syncthreads();
    bf16x8 af[4], bfr[4];
    #pragma unroll
    for (int i = 0; i < 4; i++)
      af[i] = *(const bf16x8*)&As[(wm * 64 + i * 16 + l15) * 32 + quad * 8];
    #pragma unroll
    for (int i = 0; i < 4; i++)
      bfr[i] = *(const bf16x8*)&Bs[(wn * 64 + i * 16 + l15) * 32 + quad * 8];
    #pragma unroll
    for (int i = 0; i < 4; i++)
      #pragma unroll
      for (int j = 0; j < 4; j++)
        acc[i][j] = MFMA16(af[i], bfr[j], acc[i][j]);
    __syncthreads();
  }

  #pragma unroll
  for (int i = 0; i < 4; i++) {
    int row = rowBase + wm * 64 + i * 16 + quad * 4;
    #pragma unroll
    for (int j = 0; j < 4; j++) {
      int col = colBase + wn * 64 + j * 16 + l15;
      #pragma unroll
      for (int r = 0; r < 4; r++)
        C[(size_t)(row + r) * N + col] = (OutT)acc[i][j][r];
    }
  }
}

// ---------------- flash-style GQA attention v2 ----------------
// Q pre-scaled by SCALE*log2(e) (folded into Wq) -> scores in log2 domain.
// K staged via global_load_lds into XOR-swizzled Kl[64][128]; V^T from Vg into Vt[128][64].
#define MASKV (-1e30f)

__global__ __launch_bounds__(256, 2) void gqa_attn(const bf16* __restrict__ QKV,
                                                   const bf16* __restrict__ Vg,
                                                   bf16* __restrict__ Obf) {
  __shared__ __attribute__((aligned(16))) bf16 Kl[64 * 128];   // [key][hd], chunk c' = c ^ (key&7)
  __shared__ __attribute__((aligned(16))) bf16 Vt[128 * 64];   // [hd][key], chunk c' = c ^ (d&7)
  __shared__ __attribute__((aligned(16))) bf16 Pl[4][32 * 68]; // per-wave P, stride 68

  const int tid = threadIdx.x;
  const int lane = tid & 63;
  const int wave = tid >> 6;
  const int l15 = lane & 15, quad = lane >> 4;

  // heavy/light pairing: blocks i and i+256 expected co-resident on one CU -> uniform 34 iters/CU
  int bi = blockIdx.x;
  int bh = bi & 31;
  int jj = (bi & 255) >> 5;
  int qt = (bi < 256) ? (8 + jj) : (7 - jj);
  int b = bh >> 4, h = bh & 15, kvh = h >> 2;
  int q0 = qt * 128;

  const size_t rs = 3072;
  const bf16* Qb  = QKV + (size_t)b * 2048 * rs + h * 128;
  const bf16* Kb  = QKV + (size_t)b * 2048 * rs + 2048 + kvh * 128;
  const bf16* Vgb = Vg + (size_t)(b * 4 + kvh) * 128 * 2048;

  // Q fragments (already scaled): wave owns rows [q0+wave*32, +32)
  bf16x8 qf[2][4];
  #pragma unroll
  for (int mt = 0; mt < 2; mt++) {
    int row = q0 + wave * 32 + mt * 16 + l15;
    #pragma unroll
    for (int ks = 0; ks < 4; ks++)
      qf[mt][ks] = *(const bf16x8*)&Qb[(size_t)row * rs + ks * 32 + quad * 8];
  }

  // DMA staging pointers: swizzle folded into per-lane GLOBAL address; LDS base wave-uniform.
  const bf16* kp[4]; const bf16* vp[4];
  bf16* kl[4]; bf16* vl[4];
  #pragma unroll
  for (int t = 0; t < 4; t++) {
    int keyl = wave * 16 + t * 4 + (lane >> 4);
    int ck = (lane & 15) ^ (4 * (t & 1) + (lane >> 4));  // (keyl&7) = 4*(t&1)+(lane>>4)
    kp[t] = Kb + (size_t)keyl * rs + ck * 8;
    kl[t] = &Kl[(wave * 16 + t * 4) * 128];
    int dl = wave * 32 + t * 8 + (lane >> 3);
    int cv = (lane & 7) ^ (lane >> 3);                   // (dl&7) = lane>>3
    vp[t] = Vgb + (size_t)dl * 2048 + cv * 8;
    vl[t] = &Vt[(wave * 32 + t * 8) * 64];
  }

  f32x4 oacc[2][8] = {};
  f32x4 mrow[2], lrow[2];
  #pragma unroll
  for (int mt = 0; mt < 2; mt++)
    #pragma unroll
    for (int r = 0; r < 4; r++) { mrow[mt][r] = MASKV; lrow[mt][r] = 0.f; }

  const int nkt = 2 * qt + 2;
  const int myrow_hi = q0 + wave * 32 + 31;
  for (int kt = 0; kt < nkt; kt++) {
    const int k0 = kt * 64;
    __syncthreads();  // previous tile fully consumed by all waves
    #pragma unroll
    for (int t = 0; t < 4; t++) { GLD16(kp[t], kl[t]); kp[t] += 64 * rs; }
    #pragma unroll
    for (int t = 0; t < 4; t++) { GLD16(vp[t], vl[t]); vp[t] += 64; }
    __syncthreads();  // compiler drains vmcnt before barrier -> tiles ready

    if (k0 > myrow_hi) continue;  // wave fully masked for this tile

    // S = Q K^T (log2 domain)
    f32x4 s[2][4] = {};
    #pragma unroll
    for (int ks = 0; ks < 4; ks++) {
      #pragma unroll
      for (int nt = 0; nt < 4; nt++) {
        bf16x8 kf = *(const bf16x8*)&Kl[(nt * 16 + l15) * 128 +
                                        (((ks * 4 + quad) ^ (l15 & 7)) * 8)];
        s[0][nt] = MFMA16(qf[0][ks], kf, s[0][nt]);
        s[1][nt] = MFMA16(qf[1][ks], kf, s[1][nt]);
      }
    }
    // causal mask: only the last two k-tiles can intersect the diagonal (uniform branch)
    if (kt >= nkt - 2) {
      #pragma unroll
      for (int mt = 0; mt < 2; mt++) {
        int rowb = q0 + wave * 32 + mt * 16 + quad * 4;
        #pragma unroll
        for (int nt = 0; nt < 4; nt++) {
          int col = k0 + nt * 16 + l15;
          #pragma unroll
          for (int r = 0; r < 4; r++)
            if (col > rowb + r) s[mt][nt][r] = MASKV;
        }
      }
    }
    // online softmax (log2 domain; no muls)
    #pragma unroll
    for (int mt = 0; mt < 2; mt++) {
      f32x4 mx = s[mt][0];
      #pragma unroll
      for (int nt = 1; nt < 4; nt++)
        #pragma unroll
        for (int r = 0; r < 4; r++) mx[r] = fmaxf(mx[r], s[mt][nt][r]);
      #pragma unroll
      for (int d = 1; d < 16; d <<= 1) {
        f32x4 o = shfl_xor4(mx, d);
        #pragma unroll
        for (int r = 0; r < 4; r++) mx[r] = fmaxf(mx[r], o[r]);
      }
      f32x4 mnew, alpha;
      #pragma unroll
      for (int r = 0; r < 4; r++) {
        mnew[r] = fmaxf(mrow[mt][r], mx[r]);
        alpha[r] = EXP2F(mrow[mt][r] - mnew[r]);
      }
      f32x4 rsum = {0.f, 0.f, 0.f, 0.f};
      #pragma unroll
      for (int nt = 0; nt < 4; nt++)
        #pragma unroll
        for (int r = 0; r < 4; r++) {
          float p = EXP2F(s[mt][nt][r] - mnew[r]);
          s[mt][nt][r] = p;
          rsum[r] += p;
        }
      #pragma unroll
      for (int d = 1; d < 16; d <<= 1) rsum += shfl_xor4(rsum, d);
      #pragma unroll
      for (int r = 0; r < 4; r++) {
        lrow[mt][r] = lrow[mt][r] * alpha[r] + rsum[r];
        mrow[mt][r] = mnew[r];
      }
      #pragma unroll
      for (int no = 0; no < 8; no++)
        #pragma unroll
        for (int r = 0; r < 4; r++) oacc[mt][no][r] *= alpha[r];
      // P: C-layout -> per-wave LDS (A-layout consumable); stride 68 -> conflict-free writes
      #pragma unroll
      for (int nt = 0; nt < 4; nt++)
        #pragma unroll
        for (int r = 0; r < 4; r++)
          Pl[wave][(mt * 16 + quad * 4 + r) * 68 + nt * 16 + l15] = (bf16)s[mt][nt][r];
    }
    // O += P V
    #pragma unroll
    for (int ks2 = 0; ks2 < 2; ks2++) {
      bf16x8 pf0 = *(const bf16x8*)&Pl[wave][l15 * 68 + ks2 * 32 + quad * 8];
      bf16x8 pf1 = *(const bf16x8*)&Pl[wave][(16 + l15) * 68 + ks2 * 32 + quad * 8];
      #pragma unroll
      for (int no = 0; no < 8; no++) {
        bf16x8 vf = *(const bf16x8*)&Vt[(no * 16 + l15) * 64 +
                                        (((ks2 * 4 + quad) ^ (l15 & 7)) * 8)];
        oacc[0][no] = MFMA16(pf0, vf, oacc[0][no]);
        oacc[1][no] = MFMA16(pf1, vf, oacc[1][no]);
      }
    }
  }

  // epilogue: normalize and write bf16
  #pragma unroll
  for (int mt = 0; mt < 2; mt++) {
    f32x4 linv;
    #pragma unroll
    for (int r = 0; r < 4; r++) linv[r] = 1.0f / lrow[mt][r];
    int row = q0 + wave * 32 + mt * 16 + quad * 4;
    #pragma unroll
    for (int no = 0; no < 8; no++) {
      int col = h * 128 + no * 16 + l15;
      #pragma unroll
      for (int r = 0; r < 4; r++)
        Obf[(size_t)(b * 2048 + row + r) * 2048 + col] = (bf16)(oacc[mt][no][r] * linv[r]);
    }
  }
}

extern "C" void kernel_launch(void* const* d_in, const int* in_sizes, int n_in,
                              void* d_out, int out_size, void* d_ws, size_t ws_size,
                              hipStream_t stream) {
  const float* x  = (const float*)d_in[0];
  // d_in[1] = mask: always causal tril; handled analytically.
  const float* Wq = (const float*)d_in[2];
  const float* Wk = (const float*)d_in[3];
  const float* Wv = (const float*)d_in[4];
  const float* Wo = (const float*)d_in[5];
  float* out = (float*)d_out;

  // workspace layout (bf16 elements)
  bf16* Xb    = (bf16*)d_ws;           // 4096x2048
  bf16* Wqkvt = Xb + 8388608;          // 3072x2048 (transposed, fused Q|K|V)
  bf16* Wot   = Wqkvt + 6291456;       // 2048x2048 (transposed)
  bf16* QKV   = Wot + 4194304;         // 4096x3072
  bf16* Obf   = QKV + 12582912;        // 4096x2048
  bf16* Vg    = Obf + 8388608;         // 8 x 128 x 2048 (V^T per (b,kvh))
  // total 83,886,080 bytes

  const float qscale = (float)(0.08838834764831845 * 1.4426950408889634);

  cast_f32_bf16<<<8192, 256, 0, stream>>>(x, Xb, 2097152);
  dim3 tb(32, 8);
  transpose_cast<<<dim3(64, 64), tb, 0, stream>>>(Wq, Wqkvt, 2048, 2048, 0, qscale);
  transpose_cast<<<dim3(16, 64), tb, 0, stream>>>(Wk, Wqkvt, 512, 2048, 2048, 1.0f);
  transpose_cast<<<dim3(16, 64), tb, 0, stream>>>(Wv, Wqkvt, 512, 2048, 2560, 1.0f);
  transpose_cast<<<dim3(64, 64), tb, 0, stream>>>(Wo, Wot, 2048, 2048, 0, 1.0f);

  gemm_bt<bf16><<<dim3(24, 32), 256, 0, stream>>>(Xb, Wqkvt, QKV, 4096, 3072, 2048);
  transpose_v<<<dim3(64, 4, 8), tb, 0, stream>>>(QKV, Vg);
  gqa_attn<<<512, 256, 0, stream>>>(QKV, Vg, Obf);
  gemm_bt<float><<<dim3(16, 32), 256, 0, stream>>>(Obf, Wot, out, 4096, 2048, 2048);
}